// Round 7
// baseline (850.616 us; speedup 1.0000x reference)
//
#include <hip/hip_runtime.h>
#include <cmath>

// Problem constants (fixed by reference): B=8, N=2048, eps=0.01, 50 iters.
#define BATCH 8
#define NPT   2048
#define NPAIR (NPT / 2)               // 1024 column pairs
#define NPTS  (BATCH * NPT)
#define TILES 64                      // blocks per batch (32 rows each)
#define GRID_MAIN 256                 // 1 block/CU; block owns batches (b0, b0+4)
#define THREADS 1024                  // 16 waves -> 4/SIMD
#define RPW   2                       // rows per wave per batch
#define ITERS 50

// exp(v_j - 100*cost) = exp2( C_LOG2E*v_j + NEG100C*(n_i + n_j) + S200C*dot )
#define C_LOG2E 1.4426950408889634f
#define NEG100C (-144.26950408889634f)   // -100 * log2(e)
#define S200C   288.53900817779268f      //  200 * log2(e)
#define EPS_LOG 1e-8f
#define LN2_01  0.006931471805599453f    // 0.01 * ln(2)

typedef float v2f __attribute__((ext_vector_type(2)));
typedef float v4f __attribute__((ext_vector_type(4)));
typedef unsigned long long u64t;

static __device__ __forceinline__ float fast_exp2(float x) {
#if __has_builtin(__builtin_amdgcn_exp2f)
    return __builtin_amdgcn_exp2f(x);
#else
    return exp2f(x);
#endif
}

// Guaranteed-packed fp32 ops (VOP3P); pure register asm, schedulable.
static __device__ __forceinline__ v2f pk_fma(v2f a, v2f b, v2f c) {
    v2f d;
    asm("v_pk_fma_f32 %0, %1, %2, %3" : "=v"(d) : "v"(a), "v"(b), "v"(c));
    return d;
}
static __device__ __forceinline__ v2f pk_add(v2f a, v2f b) {
    v2f d;
    asm("v_pk_add_f32 %0, %1, %2" : "=v"(d) : "v"(a), "v"(b));
    return d;
}

// Coherence-point (agent-scope, relaxed) accessors for cross-block data.
static __device__ __forceinline__ float gload(const float* p) {
    return __hip_atomic_load(p, __ATOMIC_RELAXED, __HIP_MEMORY_SCOPE_AGENT);
}
static __device__ __forceinline__ void gstore(float* p, float val) {
    __hip_atomic_store(p, val, __ATOMIC_RELAXED, __HIP_MEMORY_SCOPE_AGENT);
}
static __device__ __forceinline__ u64t gload2(const float* p) {   // 2 floats
    return __hip_atomic_load((const u64t*)p, __ATOMIC_RELAXED,
                             __HIP_MEMORY_SCOPE_AGENT);
}

// ---------------------------------------------------------------------------
__global__ void init_kernel(float* __restrict__ out,
                            unsigned int* __restrict__ flags) {
    int t = threadIdx.x;          // 512 threads
    if (t < BATCH) out[t] = 0.0f;
    flags[t] = 0u;                // BATCH*TILES = 512 flags
}

// ---------------------------------------------------------------------------
// Split barrier. arrive: all block stores drained (syncthreads vmcnt(0)),
// then one relaxed sc1 flag store. wait: wave 0's 64 lanes poll the batch's
// 64 flags with a single coherent load per round; then block-sync.
// ---------------------------------------------------------------------------
static __device__ __forceinline__ void bar_arrive(unsigned int* flags,
                                                  int slot, unsigned int ph) {
    __syncthreads();
    if (threadIdx.x == 0)
        __hip_atomic_store(&flags[slot], ph, __ATOMIC_RELAXED,
                           __HIP_MEMORY_SCOPE_AGENT);
}
static __device__ __forceinline__ void bar_wait(const unsigned int* bflags,
                                                int wave, int lane,
                                                unsigned int ph) {
    if (wave == 0) {
        while (__hip_atomic_load(&bflags[lane], __ATOMIC_RELAXED,
                                 __HIP_MEMORY_SCOPE_AGENT) < ph) {
            __builtin_amdgcn_s_sleep(1);
        }
    }
    __syncthreads();
    __builtin_amdgcn_sched_barrier(0);
}

// ---------------------------------------------------------------------------
// One Sinkhorn half-step over pair-packed LDS column tiles.
// ---------------------------------------------------------------------------
static __device__ __forceinline__ void half_pass(
        const v4f* cdXY, const v4f* cdZW,
        const v2f (&rx)[RPW], const v2f (&ry)[RPW],
        const v2f (&rz)[RPW], const v2f (&rc)[RPW],
        float* __restrict__ dual_out, int outbase, int lane, float log_mu)
{
    v2f acc[RPW];
#pragma unroll
    for (int r = 0; r < RPW; r++) acc[r] = (v2f){0.0f, 0.0f};

#pragma unroll 2
    for (int jp = 0; jp < NPAIR; jp += 64) {
        v4f a  = cdXY[jp + lane];                       // ds_read_b128
        v4f bz = cdZW[jp + lane];                       // ds_read_b128
        v2f xx = __builtin_shufflevector(a,  a,  0, 1);
        v2f yy = __builtin_shufflevector(a,  a,  2, 3);
        v2f zz = __builtin_shufflevector(bz, bz, 0, 1);
        v2f ww = __builtin_shufflevector(bz, bz, 2, 3);
#pragma unroll
        for (int r = 0; r < RPW; r++) {
            v2f t = pk_fma(xx, rx[r], ww);
            t = pk_fma(yy, ry[r], t);
            t = pk_fma(zz, rz[r], t);
            t = pk_add(t, rc[r]);
            acc[r].x += fast_exp2(t.x);
            acc[r].y += fast_exp2(t.y);
        }
    }

    float sel = 1.0f;
#pragma unroll
    for (int r = 0; r < RPW; r++) {
        float s = acc[r].x + acc[r].y;
#pragma unroll
        for (int m = 32; m >= 1; m >>= 1) s += __shfl_xor(s, m, 64);
        if (lane == r) sel = s;
    }
    float res = log_mu - __logf(sel + EPS_LOG);
    if (lane < RPW) gstore(&dual_out[outbase + lane], res);
}

// ---------------------------------------------------------------------------
// Dual-batch persistent kernel: each block owns tile `tile` of batches
// b0 and b0+4. Batch B's compute covers batch A's barrier propagation.
// LDS = 128 KB -> 1 block/CU, 16 waves/CU (4/SIMD).
// ---------------------------------------------------------------------------
__global__ __launch_bounds__(THREADS, 4) void sinkhorn_kernel(
        const float* __restrict__ x1, const float* __restrict__ x2,
        float* __restrict__ u, float* __restrict__ v,
        unsigned int* __restrict__ flags, float* __restrict__ out)
{
    __shared__ v4f c1XY[2][NPAIR], c1ZW[2][NPAIR];   // side-1 (dual = u)
    __shared__ v4f c2XY[2][NPAIR], c2ZW[2][NPAIR];   // side-2 (dual = v)

    const int b0   = blockIdx.x / TILES;      // 0..3
    const int tile = blockIdx.x % TILES;
    const int bA = b0, bB = b0 + 4;
    const int baseA = bA * NPT, baseB = bB * NPT;
    const int slotA = bA * TILES + tile, slotB = bB * TILES + tile;
    const unsigned int* flA = flags + bA * TILES;
    const unsigned int* flB = flags + bB * TILES;

    const int tid  = threadIdx.x;
    const int wave = tid >> 6;
    const int lane = tid & 63;
    const int row0 = tile * 32 + wave * RPW;

    const float log_mu = logf(1.0f / (float)NPT + EPS_LOG);

    // ---- one-time staging: thread t stages pair t for both sides/batches --
    float P1a[2], P1b[2], P2a[2], P2b[2];    // [g]: even/odd point of pair
#pragma unroll
    for (int g = 0; g < 2; g++) {
        int base = g ? baseB : baseA;
        const float* p = x1 + 3 * (base + 2 * tid);
        float ax = p[0], ay = p[1], az = p[2];
        float bx = p[3], by = p[4], bz = p[5];
        float na = fmaf(ax, ax, fmaf(ay, ay, az * az));
        float nb = fmaf(bx, bx, fmaf(by, by, bz * bz));
        P1a[g] = na * NEG100C;  P1b[g] = nb * NEG100C;
        c1XY[g][tid] = (v4f){ax * S200C, bx * S200C, ay * S200C, by * S200C};
        c1ZW[g][tid] = (v4f){az * S200C, bz * S200C, P1a[g], P1b[g]};

        p = x2 + 3 * (base + 2 * tid);
        ax = p[0]; ay = p[1]; az = p[2];
        bx = p[3]; by = p[4]; bz = p[5];
        na = fmaf(ax, ax, fmaf(ay, ay, az * az));
        nb = fmaf(bx, bx, fmaf(by, by, bz * bz));
        P2a[g] = na * NEG100C;  P2b[g] = nb * NEG100C;
        c2XY[g][tid] = (v4f){ax * S200C, bx * S200C, ay * S200C, by * S200C};
        c2ZW[g][tid] = (v4f){az * S200C, bz * S200C, P2a[g], P2b[g]};
    }

    // ---- one-time row registers (wave-uniform splats), per batch ----
    v2f rx1[2][RPW], ry1[2][RPW], rz1[2][RPW], rc1[2][RPW];
    v2f rx2[2][RPW], ry2[2][RPW], rz2[2][RPW], rc2[2][RPW];
    float rc1s[2][RPW];
#pragma unroll
    for (int g = 0; g < 2; g++) {
        int base = g ? baseB : baseA;
#pragma unroll
        for (int r = 0; r < RPW; r++) {
            const float* p = x1 + 3 * (base + row0 + r);
            float a = p[0], bb = p[1], c = p[2];
            float nn = NEG100C * fmaf(a, a, fmaf(bb, bb, c * c));
            rx1[g][r] = (v2f){a, a};  ry1[g][r] = (v2f){bb, bb};
            rz1[g][r] = (v2f){c, c};  rc1[g][r] = (v2f){nn, nn};
            rc1s[g][r] = nn;
            p = x2 + 3 * (base + row0 + r);
            a = p[0]; bb = p[1]; c = p[2];
            nn = NEG100C * fmaf(a, a, fmaf(bb, bb, c * c));
            rx2[g][r] = (v2f){a, a};  ry2[g][r] = (v2f){bb, bb};
            rz2[g][r] = (v2f){c, c};  rc2[g][r] = (v2f){nn, nn};
        }
    }
    __syncthreads();

    // ---- 50 Sinkhorn iterations; B-compute hides A-barrier latency ----
    unsigned int ph = 0;
    for (int it = 0; it < ITERS; it++) {
        // u = log_mu - log(K e^v): side-2 tiles
        half_pass(c2XY[0], c2ZW[0], rx1[0], ry1[0], rz1[0], rc1[0],
                  u, baseA + row0, lane, log_mu);
        bar_arrive(flags, slotA, ph + 1);
        half_pass(c2XY[1], c2ZW[1], rx1[1], ry1[1], rz1[1], rc1[1],
                  u, baseB + row0, lane, log_mu);
        bar_arrive(flags, slotB, ph + 1);
        bar_wait(flA, wave, lane, ph + 1);
        bar_wait(flB, wave, lane, ph + 1);
        {   // fold fresh u into side-1 w-slots (loads overlap A/B)
            u64t dA = gload2(u + baseA + 2 * tid);
            u64t dB = gload2(u + baseB + 2 * tid);
            float aA = __uint_as_float((unsigned)dA);
            float bA2 = __uint_as_float((unsigned)(dA >> 32));
            float aB = __uint_as_float((unsigned)dB);
            float bB2 = __uint_as_float((unsigned)(dB >> 32));
            reinterpret_cast<v2f*>(&c1ZW[0][tid])[1] =
                (v2f){fmaf(C_LOG2E, aA, P1a[0]), fmaf(C_LOG2E, bA2, P1b[0])};
            reinterpret_cast<v2f*>(&c1ZW[1][tid])[1] =
                (v2f){fmaf(C_LOG2E, aB, P1a[1]), fmaf(C_LOG2E, bB2, P1b[1])};
        }
        __syncthreads();

        // v = log_nu - log(K^T e^u): side-1 tiles
        half_pass(c1XY[0], c1ZW[0], rx2[0], ry2[0], rz2[0], rc2[0],
                  v, baseA + row0, lane, log_mu);
        bar_arrive(flags, slotA, ph + 2);
        half_pass(c1XY[1], c1ZW[1], rx2[1], ry2[1], rz2[1], rc2[1],
                  v, baseB + row0, lane, log_mu);
        bar_arrive(flags, slotB, ph + 2);
        bar_wait(flA, wave, lane, ph + 2);
        bar_wait(flB, wave, lane, ph + 2);
        if (it < ITERS - 1) {   // fold fresh v into side-2 w-slots
            u64t dA = gload2(v + baseA + 2 * tid);
            u64t dB = gload2(v + baseB + 2 * tid);
            float aA = __uint_as_float((unsigned)dA);
            float bA2 = __uint_as_float((unsigned)(dA >> 32));
            float aB = __uint_as_float((unsigned)dB);
            float bB2 = __uint_as_float((unsigned)(dB >> 32));
            reinterpret_cast<v2f*>(&c2ZW[0][tid])[1] =
                (v2f){fmaf(C_LOG2E, aA, P2a[0]), fmaf(C_LOG2E, bA2, P2b[0])};
            reinterpret_cast<v2f*>(&c2ZW[1][tid])[1] =
                (v2f){fmaf(C_LOG2E, aB, P2a[1]), fmaf(C_LOG2E, bB2, P2b[1])};
        }
        __syncthreads();
        ph += 2;
    }

    // ---- fused EMD epilogue (both batches):
    //      cost = 0.01*(u_i+v_j) - 0.01*ln2 * t  (algebraically exact) ----
    v2f* cvp0 = reinterpret_cast<v2f*>(c1XY[0]);   // reused, no other reader
    v2f* cvp1 = reinterpret_cast<v2f*>(c1XY[1]);
    {
        u64t dA = gload2(v + baseA + 2 * tid);
        u64t dB = gload2(v + baseB + 2 * tid);
        float aA = __uint_as_float((unsigned)dA);
        float bA2 = __uint_as_float((unsigned)(dA >> 32));
        float aB = __uint_as_float((unsigned)dB);
        float bB2 = __uint_as_float((unsigned)(dB >> 32));
        reinterpret_cast<v2f*>(&c2ZW[0][tid])[1] =
            (v2f){fmaf(C_LOG2E, aA, P2a[0]), fmaf(C_LOG2E, bA2, P2b[0])};
        reinterpret_cast<v2f*>(&c2ZW[1][tid])[1] =
            (v2f){fmaf(C_LOG2E, aB, P2a[1]), fmaf(C_LOG2E, bB2, P2b[1])};
        cvp0[tid] = (v2f){0.01f * aA, 0.01f * bA2};
        cvp1[tid] = (v2f){0.01f * aB, 0.01f * bB2};
    }
    __syncthreads();

    const v2f NL2 = {-LN2_01, -LN2_01};
    float es[2];
#pragma unroll
    for (int g = 0; g < 2; g++) {
        int base = g ? baseB : baseA;
        v2f* cvp = g ? cvp1 : cvp0;
        v2f rcc[RPW], su[RPW];
#pragma unroll
        for (int r = 0; r < RPW; r++) {
            float ur  = gload(&u[base + row0 + r]);
            float rcs = fmaf(C_LOG2E, ur, rc1s[g][r]);
            rcc[r] = (v2f){rcs, rcs};
            float sus = 0.01f * ur;
            su[r] = (v2f){sus, sus};
        }
        v2f eacc = {0.0f, 0.0f};
#pragma unroll 2
        for (int jp = 0; jp < NPAIR; jp += 64) {
            v4f a   = c2XY[g][jp + lane];
            v4f bz  = c2ZW[g][jp + lane];
            v2f cv2 = cvp[jp + lane];
            v2f xx = __builtin_shufflevector(a,  a,  0, 1);
            v2f yy = __builtin_shufflevector(a,  a,  2, 3);
            v2f zz = __builtin_shufflevector(bz, bz, 0, 1);
            v2f ww = __builtin_shufflevector(bz, bz, 2, 3);
#pragma unroll
            for (int r = 0; r < RPW; r++) {
                v2f t = pk_fma(xx, rx1[g][r], ww);
                t = pk_fma(yy, ry1[g][r], t);
                t = pk_fma(zz, rz1[g][r], t);
                t = pk_add(t, rcc[r]);
                v2f c2 = pk_fma(t, NL2, pk_add(su[r], cv2));
                eacc.x = fmaf(fast_exp2(t.x), c2.x, eacc.x);
                eacc.y = fmaf(fast_exp2(t.y), c2.y, eacc.y);
            }
        }
        float e = eacc.x + eacc.y;
#pragma unroll
        for (int m = 32; m >= 1; m >>= 1) e += __shfl_xor(e, m, 64);
        es[g] = e;
    }

    float* wsumA = reinterpret_cast<float*>(c1ZW[0]);  // unused in epilogue
    float* wsumB = reinterpret_cast<float*>(c1ZW[1]);
    if (lane == 0) { wsumA[wave] = es[0]; wsumB[wave] = es[1]; }
    __syncthreads();
    if (tid == 0) {
        float sA = 0.0f, sB = 0.0f;
#pragma unroll
        for (int w = 0; w < THREADS / 64; w++) { sA += wsumA[w]; sB += wsumB[w]; }
        atomicAdd(&out[bA], sA);
        atomicAdd(&out[bB], sB);
    }
}

// ---------------------------------------------------------------------------
extern "C" void kernel_launch(void* const* d_in, const int* in_sizes, int n_in,
                              void* d_out, int out_size, void* d_ws, size_t ws_size,
                              hipStream_t stream) {
    (void)in_sizes; (void)n_in; (void)out_size; (void)ws_size;
    const float* x1 = (const float*)d_in[0];
    const float* x2 = (const float*)d_in[1];
    float* out = (float*)d_out;

    char* ws = (char*)d_ws;
    float* u = (float*)ws;                             // NPTS floats
    float* v = u + NPTS;                               // NPTS floats
    unsigned int* flags = (unsigned int*)(v + NPTS);   // BATCH*TILES uints

    init_kernel<<<1, 512, 0, stream>>>(out, flags);
    sinkhorn_kernel<<<GRID_MAIN, THREADS, 0, stream>>>(x1, x2, u, v, flags, out);
}

// Round 8
// 813.716 us; speedup vs baseline: 1.0453x; 1.0453x over previous
//
#include <hip/hip_runtime.h>
#include <cmath>

// Problem constants (fixed by reference): B=8, N=2048, eps=0.01, 50 iters.
#define BATCH 8
#define NPT   2048
#define NPAIR (NPT / 2)               // 1024 column pairs
#define NPTS  (BATCH * NPT)
#define TILES 64                      // blocks per batch (32 rows each)
#define GRID_MAIN (BATCH * TILES)     // 512 blocks = 2/CU (64KB LDS -> both resident)
#define THREADS 512                   // 8 waves -> 16 waves/CU = 4/SIMD
#define ITERS 50

// exp(v_j - 100*cost) = exp2( C_LOG2E*v_j + NEG100C*(n_i + n_j) + S200C*dot )
#define C_LOG2E 1.4426950408889634f
#define NEG100C (-144.26950408889634f)   // -100 * log2(e)
#define S200C   288.53900817779268f      //  200 * log2(e)
#define EPS_LOG 1e-8f
#define LN2_01  0.006931471805599453f    // 0.01 * ln(2)

typedef float v2f __attribute__((ext_vector_type(2)));
typedef float v4f __attribute__((ext_vector_type(4)));
typedef unsigned long long u64t;

static __device__ __forceinline__ float fast_exp2(float x) {
#if __has_builtin(__builtin_amdgcn_exp2f)
    return __builtin_amdgcn_exp2f(x);
#else
    return exp2f(x);
#endif
}

// Guaranteed-packed fp32 ops (VOP3P); pure register asm, schedulable.
static __device__ __forceinline__ v2f pk_fma(v2f a, v2f b, v2f c) {
    v2f d;
    asm("v_pk_fma_f32 %0, %1, %2, %3" : "=v"(d) : "v"(a), "v"(b), "v"(c));
    return d;
}
static __device__ __forceinline__ v2f pk_add(v2f a, v2f b) {
    v2f d;
    asm("v_pk_add_f32 %0, %1, %2" : "=v"(d) : "v"(a), "v"(b));
    return d;
}

// Coherence-point (agent-scope, relaxed) accessors for cross-block data.
static __device__ __forceinline__ float gload(const float* p) {
    return __hip_atomic_load(p, __ATOMIC_RELAXED, __HIP_MEMORY_SCOPE_AGENT);
}
static __device__ __forceinline__ void gstore(float* p, float val) {
    __hip_atomic_store(p, val, __ATOMIC_RELAXED, __HIP_MEMORY_SCOPE_AGENT);
}
static __device__ __forceinline__ u64t gload2(const float* p) {   // 2 floats
    return __hip_atomic_load((const u64t*)p, __ATOMIC_RELAXED,
                             __HIP_MEMORY_SCOPE_AGENT);
}

// ---------------------------------------------------------------------------
__global__ void init_kernel(float* __restrict__ out,
                            unsigned int* __restrict__ flags) {
    int t = threadIdx.x;          // 512 threads
    if (t < BATCH) out[t] = 0.0f;
    flags[t] = 0u;                // BATCH*TILES = 512 flags
}

// ---------------------------------------------------------------------------
// Flag-array barrier: NO atomic RMW, NO acquire ops (proven in R4-R7).
// ---------------------------------------------------------------------------
static __device__ __forceinline__ void flag_barrier(unsigned int* bflags,
                                                    int tile, int wave,
                                                    int lane,
                                                    unsigned int phase) {
    __syncthreads();
    if (wave == 0) {
        if (lane == 0)
            __hip_atomic_store(&bflags[tile], phase, __ATOMIC_RELAXED,
                               __HIP_MEMORY_SCOPE_AGENT);
        while (__hip_atomic_load(&bflags[lane], __ATOMIC_RELAXED,
                                 __HIP_MEMORY_SCOPE_AGENT) < phase) {
            __builtin_amdgcn_s_sleep(1);
        }
    }
    __syncthreads();
    __builtin_amdgcn_sched_barrier(0);
}

// ---------------------------------------------------------------------------
// Fold fresh dual values into the w-slots of a ZW tile (R5-proven layout:
// thread t owns pairs {2t, 2t+1}; two 8-byte coherent loads).
// ---------------------------------------------------------------------------
static __device__ __forceinline__ void fold_dual(v4f* cdZW, const float* dual,
        int base, int tid, const float (&Pa)[2], const float (&Pb)[2]) {
    u64t d0 = gload2(dual + base + 4 * tid);
    u64t d1 = gload2(dual + base + 4 * tid + 2);
    float a0 = __uint_as_float((unsigned)d0);
    float b0 = __uint_as_float((unsigned)(d0 >> 32));
    float a1 = __uint_as_float((unsigned)d1);
    float b1 = __uint_as_float((unsigned)(d1 >> 32));
    reinterpret_cast<v2f*>(&cdZW[2 * tid])[1] =
        (v2f){fmaf(C_LOG2E, a0, Pa[0]), fmaf(C_LOG2E, b0, Pb[0])};
    reinterpret_cast<v2f*>(&cdZW[2 * tid + 1])[1] =
        (v2f){fmaf(C_LOG2E, a1, Pa[1]), fmaf(C_LOG2E, b1, Pb[1])};
}

// ---------------------------------------------------------------------------
// Row-per-lane half-pass core: lane owns ONE row (splatted constants);
// columns stream as (half-)wave-uniform b128 reads (broadcast, ~0 BW).
// Returns this lane's partial sum over its 64 pairs (128 columns).
// ---------------------------------------------------------------------------
static __device__ __forceinline__ float half_core(
        const v4f* cdXY, const v4f* cdZW, int p0,
        v2f RX, v2f RY, v2f RZ, v2f RC)
{
    float accx = 0.0f, accy = 0.0f;
#pragma unroll 4
    for (int s = 0; s < 64; s++) {
        v4f a  = cdXY[p0 + s];                      // uniform ds_read_b128
        v4f bz = cdZW[p0 + s];                      // uniform ds_read_b128
        v2f xx = __builtin_shufflevector(a,  a,  0, 1);
        v2f yy = __builtin_shufflevector(a,  a,  2, 3);
        v2f zz = __builtin_shufflevector(bz, bz, 0, 1);
        v2f ww = __builtin_shufflevector(bz, bz, 2, 3);
        v2f t = pk_fma(xx, RX, ww);
        t = pk_fma(yy, RY, t);
        t = pk_fma(zz, RZ, t);
        t = pk_add(t, RC);
        accx += fast_exp2(t.x);
        accy += fast_exp2(t.y);
    }
    return accx + accy;
}

// ---------------------------------------------------------------------------
// Fused persistent kernel, row-per-lane layout.
// lane&31 -> local row; lane>>5 -> column half; wave scans 128 pairs.
// LDS = 64 KB tiles + 1.2 KB reduce pad; 2 blocks/CU, 4 waves/SIMD.
// ---------------------------------------------------------------------------
__global__ __launch_bounds__(THREADS, 4) void sinkhorn_kernel(
        const float* __restrict__ x1, const float* __restrict__ x2,
        float* __restrict__ u, float* __restrict__ v,
        unsigned int* __restrict__ flags, float* __restrict__ out)
{
    __shared__ v4f cd1XY[NPAIR], cd1ZW[NPAIR];   // side-1 (dual = u)
    __shared__ v4f cd2XY[NPAIR], cd2ZW[NPAIR];   // side-2 (dual = v)
    __shared__ float part[32][9];                // padded cross-wave reduce

    const int b    = blockIdx.x / TILES;
    const int tile = blockIdx.x % TILES;
    const int base = b * NPT;
    unsigned int* bflags = flags + b * TILES;

    const int tid  = threadIdx.x;
    const int wave = tid >> 6;
    const int lane = tid & 63;
    const int rloc = lane & 31;              // local row 0..31
    const int ch   = lane >> 5;              // column half 0/1
    const int row  = tile * 32 + rloc;       // global row in batch
    const int p0   = wave * 128 + ch * 64;   // this lane's pair base

    const float log_mu = logf(1.0f / (float)NPT + EPS_LOG);

    // ---- one-time staging: thread t stages pairs {2t, 2t+1} ----
    float P1a[2], P1b[2], P2a[2], P2b[2];
#pragma unroll
    for (int k = 0; k < 2; k++) {
        int q = 2 * tid + k;
        const float* p = x1 + 3 * (base + 2 * q);
        float ax = p[0], ay = p[1], az = p[2];
        float bx = p[3], by = p[4], bz = p[5];
        float na = fmaf(ax, ax, fmaf(ay, ay, az * az));
        float nb = fmaf(bx, bx, fmaf(by, by, bz * bz));
        P1a[k] = na * NEG100C;  P1b[k] = nb * NEG100C;
        cd1XY[q] = (v4f){ax * S200C, bx * S200C, ay * S200C, by * S200C};
        cd1ZW[q] = (v4f){az * S200C, bz * S200C, P1a[k], P1b[k]};

        p = x2 + 3 * (base + 2 * q);
        ax = p[0]; ay = p[1]; az = p[2];
        bx = p[3]; by = p[4]; bz = p[5];
        na = fmaf(ax, ax, fmaf(ay, ay, az * az));
        nb = fmaf(bx, bx, fmaf(by, by, bz * bz));
        P2a[k] = na * NEG100C;  P2b[k] = nb * NEG100C;
        cd2XY[q] = (v4f){ax * S200C, bx * S200C, ay * S200C, by * S200C};
        cd2ZW[q] = (v4f){az * S200C, bz * S200C, P2a[k], P2b[k]};
    }

    // ---- lane's single-row constants (splatted), both sides ----
    v2f RX1, RY1, RZ1, RC1, RX2, RY2, RZ2, RC2;
    float rc1s;
    {
        const float* p = x1 + 3 * (base + row);
        float a = p[0], bb = p[1], c = p[2];
        float nn = NEG100C * fmaf(a, a, fmaf(bb, bb, c * c));
        RX1 = (v2f){a, a};  RY1 = (v2f){bb, bb};
        RZ1 = (v2f){c, c};  RC1 = (v2f){nn, nn};
        rc1s = nn;
        p = x2 + 3 * (base + row);
        a = p[0]; bb = p[1]; c = p[2];
        nn = NEG100C * fmaf(a, a, fmaf(bb, bb, c * c));
        RX2 = (v2f){a, a};  RY2 = (v2f){bb, bb};
        RZ2 = (v2f){c, c};  RC2 = (v2f){nn, nn};
    }
    __syncthreads();

    // ---- 50 Sinkhorn iterations, 2 flag barriers each ----
    unsigned int ph = 0;
    for (int it = 0; it < ITERS; it++) {
        if (it > 0) {   // fold fresh v into cd2 w-slots (iter 0: w=P already)
            fold_dual(cd2ZW, v, base, tid, P2a, P2b);
            __syncthreads();
        }
        // u_i = log_mu - log(sum_j K_ij e^{v_j} + eps)
        {
            float s = half_core(cd2XY, cd2ZW, p0, RX1, RY1, RZ1, RC1);
            s += __shfl_xor(s, 32, 64);          // combine column halves
            if (lane < 32) part[rloc][wave] = s;
            __syncthreads();
            if (wave == 0) {
                float t = 0.0f;
#pragma unroll
                for (int w = 0; w < 8; w++) t += part[rloc][w];
                float res = log_mu - __logf(t + EPS_LOG);
                if (lane < 32) gstore(&u[base + row], res);   // coalesced 128B
            }
        }
        flag_barrier(bflags, tile, wave, lane, ++ph);   // publish u

        fold_dual(cd1ZW, u, base, tid, P1a, P1b);       // fold fresh u
        __syncthreads();
        // v_j = log_nu - log(sum_i K_ij e^{u_i} + eps)
        {
            float s = half_core(cd1XY, cd1ZW, p0, RX2, RY2, RZ2, RC2);
            s += __shfl_xor(s, 32, 64);
            if (lane < 32) part[rloc][wave] = s;
            __syncthreads();
            if (wave == 0) {
                float t = 0.0f;
#pragma unroll
                for (int w = 0; w < 8; w++) t += part[rloc][w];
                float res = log_mu - __logf(t + EPS_LOG);
                if (lane < 32) gstore(&v[base + row], res);
            }
        }
        flag_barrier(bflags, tile, wave, lane, ++ph);   // publish v
    }

    // ---- fused EMD epilogue: emd[b] = sum_ij exp2(t) * cost,
    //      cost = 0.01*(u_i+v_j) - 0.01*ln2 * t  (algebraically exact) ----
    v2f* cvp = reinterpret_cast<v2f*>(cd1XY);   // cd1XY space reused
    {
        u64t d0 = gload2(v + base + 4 * tid);
        u64t d1 = gload2(v + base + 4 * tid + 2);
        float a0 = __uint_as_float((unsigned)d0);
        float b0 = __uint_as_float((unsigned)(d0 >> 32));
        float a1 = __uint_as_float((unsigned)d1);
        float b1 = __uint_as_float((unsigned)(d1 >> 32));
        reinterpret_cast<v2f*>(&cd2ZW[2 * tid])[1] =
            (v2f){fmaf(C_LOG2E, a0, P2a[0]), fmaf(C_LOG2E, b0, P2b[0])};
        reinterpret_cast<v2f*>(&cd2ZW[2 * tid + 1])[1] =
            (v2f){fmaf(C_LOG2E, a1, P2a[1]), fmaf(C_LOG2E, b1, P2b[1])};
        cvp[2 * tid]     = (v2f){0.01f * a0, 0.01f * b0};
        cvp[2 * tid + 1] = (v2f){0.01f * a1, 0.01f * b1};
    }
    __syncthreads();

    float ur = gload(&u[base + row]);
    float rcs = fmaf(C_LOG2E, ur, rc1s);
    v2f RCC = (v2f){rcs, rcs};
    float sus = 0.01f * ur;
    v2f SU = (v2f){sus, sus};

    const v2f NL2 = {-LN2_01, -LN2_01};
    v2f eacc = {0.0f, 0.0f};
#pragma unroll 4
    for (int s = 0; s < 64; s++) {
        v4f a   = cd2XY[p0 + s];
        v4f bz  = cd2ZW[p0 + s];
        v2f cv2 = cvp[p0 + s];
        v2f xx = __builtin_shufflevector(a,  a,  0, 1);
        v2f yy = __builtin_shufflevector(a,  a,  2, 3);
        v2f zz = __builtin_shufflevector(bz, bz, 0, 1);
        v2f ww = __builtin_shufflevector(bz, bz, 2, 3);
        v2f t = pk_fma(xx, RX1, ww);
        t = pk_fma(yy, RY1, t);
        t = pk_fma(zz, RZ1, t);
        t = pk_add(t, RCC);
        v2f c2 = pk_fma(t, NL2, pk_add(SU, cv2));
        eacc.x = fmaf(fast_exp2(t.x), c2.x, eacc.x);
        eacc.y = fmaf(fast_exp2(t.y), c2.y, eacc.y);
    }
    float es = eacc.x + eacc.y;
#pragma unroll
    for (int m = 32; m >= 1; m >>= 1) es += __shfl_xor(es, m, 64);

    __syncthreads();                      // part[] free for reuse
    if (lane == 0) part[0][wave] = es;
    __syncthreads();
    if (tid == 0) {
        float s = 0.0f;
#pragma unroll
        for (int w = 0; w < 8; w++) s += part[0][w];
        atomicAdd(&out[b], s);
    }
}

// ---------------------------------------------------------------------------
extern "C" void kernel_launch(void* const* d_in, const int* in_sizes, int n_in,
                              void* d_out, int out_size, void* d_ws, size_t ws_size,
                              hipStream_t stream) {
    (void)in_sizes; (void)n_in; (void)out_size; (void)ws_size;
    const float* x1 = (const float*)d_in[0];
    const float* x2 = (const float*)d_in[1];
    float* out = (float*)d_out;

    char* ws = (char*)d_ws;
    float* u = (float*)ws;                             // NPTS floats
    float* v = u + NPTS;                               // NPTS floats
    unsigned int* flags = (unsigned int*)(v + NPTS);   // BATCH*TILES uints

    init_kernel<<<1, 512, 0, stream>>>(out, flags);
    sinkhorn_kernel<<<GRID_MAIN, THREADS, 0, stream>>>(x1, x2, u, v, flags, out);
}